// Round 4
// baseline (260.779 us; speedup 1.0000x reference)
//
#include <hip/hip_runtime.h>
#include <math.h>

#define BB 16
#define NP 8192
#define NV 42
#define NF 80
#define FEAT 256
#define PPB 64           // points per block (mvc)
#define CHF 10           // faces per wave-chunk
#define NWV 8            // waves per mvc block
#define WST 67           // padded LDS stride for wj

// Icosphere(level=1) face table — deterministic from ico_sphere_np(1)
// (midpoint-cache construction traced exactly; verts 0-11 base, 12-41 mids).
#define FACE_LIST \
 {0,12,14},{11,13,12},{5,14,13},{12,13,14}, \
 {0,14,16},{5,15,14},{1,16,15},{14,15,16}, \
 {0,16,18},{1,17,16},{7,18,17},{16,17,18}, \
 {0,18,20},{7,19,18},{10,20,19},{18,19,20}, \
 {0,20,12},{10,21,20},{11,12,21},{20,21,12}, \
 {1,15,23},{5,22,15},{9,23,22},{15,22,23}, \
 {5,13,25},{11,24,13},{4,25,24},{13,24,25}, \
 {11,21,27},{10,26,21},{2,27,26},{21,26,27}, \
 {10,19,29},{7,28,19},{6,29,28},{19,28,29}, \
 {7,17,31},{1,30,17},{8,31,30},{17,30,31}, \
 {3,32,34},{9,33,32},{4,34,33},{32,33,34}, \
 {3,34,36},{4,35,34},{2,36,35},{34,35,36}, \
 {3,36,38},{2,37,36},{6,38,37},{36,37,38}, \
 {3,38,40},{6,39,38},{8,40,39},{38,39,40}, \
 {3,40,32},{8,41,40},{9,32,41},{40,41,32}, \
 {4,33,25},{9,22,33},{5,25,22},{33,22,25}, \
 {2,35,27},{4,24,35},{11,27,24},{35,24,27}, \
 {6,37,29},{2,26,37},{10,29,26},{37,26,29}, \
 {8,39,31},{6,28,39},{7,31,28},{39,28,31}, \
 {9,41,23},{8,30,41},{1,23,30},{41,30,23}

constexpr int FC[NF][3] = { FACE_LIST };             // compile-time
static __device__ const int FR[NF][3] = { FACE_LIST }; // runtime (cold paths)

constexpr unsigned long long chunk_vmask(int q) {
  unsigned long long m = 0;
  for (int f = q * CHF; f < q * CHF + CHF; ++f)
    for (int k = 0; k < 3; ++k) m |= 1ull << FC[f][k];
  return m;
}

__device__ __forceinline__ float rcp_f(float x)  { return __builtin_amdgcn_rcpf(x); }
__device__ __forceinline__ float rsq_f(float x)  { return __builtin_amdgcn_rsqf(x); }
__device__ __forceinline__ float sqrt_f(float x) { return __builtin_amdgcn_sqrtf(x); }

// theta = 2*asin(x), x in [0,1). Branchless, |err|~1e-5.
__device__ __forceinline__ float theta_from_x(float x) {
  bool big = x > 0.5f;
  float z = big ? fmaf(-0.5f, x, 0.5f) : x * x;
  float s = big ? sqrt_f(z) : x;
  float P = fmaf(z, 0.022371875f, 0.030381944f);
  P = fmaf(z, P, 0.044642857f);
  P = fmaf(z, P, 0.075f);
  P = fmaf(z, P, 0.16666667f);
  float r = fmaf(s * z, P, s);
  return big ? fmaf(-4.f, r, 3.14159265358979f) : 2.f * r;
}

// ---- per-chunk vertex hoist (compile-time touched set) ----
template<int Q, int C>
struct Vtx {
  static __device__ __forceinline__ void go(const float4* vpos,
      float qx, float qy, float qz,
      float (&ux)[NV], float (&uy)[NV], float (&uz)[NV], float (&dd)[NV],
      unsigned long long& closeMask) {
    if constexpr (C < NV) {
      if constexpr ((chunk_vmask(Q) >> C) & 1ull) {
        float4 v = vpos[C];
        float ax = v.x - qx, ay = v.y - qy, az = v.z - qz;
        float ss = fmaf(ax, ax, fmaf(ay, ay, az * az));
        if (ss < 1e-16f) closeMask |= (1ull << C);   // d<1e-8 <=> ss<1e-16
        float ir = rsq_f(ss);
        ux[C] = ax * ir; uy[C] = ay * ir; uz[C] = az * ir; dd[C] = ss * ir;
      }
      Vtx<Q, C + 1>::go(vpos, qx, qy, qz, ux, uy, uz, dd, closeMask);
    }
  }
};

// ---- one face, fully compile-time indices ----
template<int F>
__device__ __forceinline__ void face_body(
    const float (&ux)[NV], const float (&uy)[NV], const float (&uz)[NV],
    const float (&dd)[NV], float (&wj)[NV], int& anyInside)
{
  constexpr int f0 = FC[F][0], f1 = FC[F][1], f2 = FC[F][2];
  float ex = ux[f1] - ux[f2], ey = uy[f1] - uy[f2], ez = uz[f1] - uz[f2];
  float x0 = 0.5f * sqrt_f(fmaf(ex, ex, fmaf(ey, ey, ez * ez)));
  ex = ux[f2] - ux[f0]; ey = uy[f2] - uy[f0]; ez = uz[f2] - uz[f0];
  float x1 = 0.5f * sqrt_f(fmaf(ex, ex, fmaf(ey, ey, ez * ez)));
  ex = ux[f0] - ux[f1]; ey = uy[f0] - uy[f1]; ez = uz[f0] - uz[f1];
  float x2 = 0.5f * sqrt_f(fmaf(ex, ex, fmaf(ey, ey, ez * ez)));
  if (x0 >= 1.f) x0 = 0.99999f;
  if (x1 >= 1.f) x1 = 0.99999f;
  if (x2 >= 1.f) x2 = 0.99999f;
  float cx0 = sqrt_f(fmaxf(fmaf(-x0, x0, 1.f), 0.f));
  float cx1 = sqrt_f(fmaxf(fmaf(-x1, x1, 1.f), 0.f));
  float cx2 = sqrt_f(fmaxf(fmaf(-x2, x2, 1.f), 0.f));
  float th0 = theta_from_x(x0);
  float th1 = theta_from_x(x1);
  float th2 = theta_from_x(x2);
  float hh = 0.5f * ((th0 + th1) + th2);
  if (3.14159265358979f - hh < 1e-4f) anyInside = 1;
  float st0 = 2.f * (x0 * cx0);
  float st1 = 2.f * (x1 * cx1);
  float st2 = 2.f * (x2 * cx2);
  float A1 = x0 * (cx1 * cx2);
  float A2 = x1 * (cx0 * cx2);
  float A3 = x2 * (cx0 * cx1);
  float A4 = x0 * (x1 * x2);
  float sh  = ((A1 + A2) + A3) - A4;     // sin(h)
  float sm0 = ((-A1 + A2) + A3) + A4;    // sin(h-th0)
  float sm1 = ((A1 - A2) + A3) + A4;
  float sm2 = ((A1 + A2) - A3) + A4;
  float twosh = 2.f * sh;
  float c0 = fmaf(twosh * sm0, rcp_f(st1 * st2), -1.f);
  float c1 = fmaf(twosh * sm1, rcp_f(st2 * st0), -1.f);
  float c2 = fmaf(twosh * sm2, rcp_f(st0 * st1), -1.f);
  c0 = fminf(fmaxf(c0, -0.99999f), 0.99999f);
  c1 = fminf(fmaxf(c1, -0.99999f), 0.99999f);
  c2 = fminf(fmaxf(c2, -0.99999f), 0.99999f);
  float det = ux[f0] * fmaf(uy[f1], uz[f2], -(uz[f1] * uy[f2]))
            - uy[f0] * fmaf(ux[f1], uz[f2], -(uz[f1] * ux[f2]))
            + uz[f0] * fmaf(ux[f1], uy[f2], -(uy[f1] * ux[f2]));
  float sg = (det > 0.f) ? 1.f : ((det < 0.f) ? -1.f : 0.f);
  float s0 = sg * sqrt_f(fmaf(-c0, c0, 1.f));
  float s1 = sg * sqrt_f(fmaf(-c1, c1, 1.f));
  float s2 = sg * sqrt_f(fmaf(-c2, c2, 1.f));
  float w0 = fmaf(-c2, th1, fmaf(-c1, th2, th0)) * rcp_f((dd[f0] * st1) * s2);
  float w1 = fmaf(-c0, th2, fmaf(-c2, th0, th1)) * rcp_f((dd[f1] * st2) * s0);
  float w2 = fmaf(-c1, th0, fmaf(-c0, th1, th2)) * rcp_f((dd[f2] * st0) * s1);
  wj[f0] += w0;
  wj[f1] += w1;
  wj[f2] += w2;
}

template<int Q, int K>
struct FaceChain {
  static __device__ __forceinline__ void go(
      const float (&ux)[NV], const float (&uy)[NV], const float (&uz)[NV],
      const float (&dd)[NV], float (&wj)[NV], int& anyInside) {
    if constexpr (K < CHF) {
      face_body<Q * CHF + K>(ux, uy, uz, dd, wj, anyInside);
      FaceChain<Q, K + 1>::go(ux, uy, uz, dd, wj, anyInside);
    }
  }
};

template<int Q, int C>
struct AddChain {
  static __device__ __forceinline__ void go(float* wjLDS, int p,
                                            const float (&wj)[NV]) {
    if constexpr (C < NV) {
      if constexpr ((chunk_vmask(Q) >> C) & 1ull)
        atomicAdd(&wjLDS[C * WST + p], wj[C]);
      AddChain<Q, C + 1>::go(wjLDS, p, wj);
    }
  }
};

template<int Q>
__device__ __forceinline__ void do_chunk(const float4* vpos,
    float qx, float qy, float qz, float* wjLDS, int p,
    int& anyInside, unsigned long long& closeMask)
{
  float ux[NV], uy[NV], uz[NV], dd[NV];
  float wj[NV] = {};
  Vtx<Q, 0>::go(vpos, qx, qy, qz, ux, uy, uz, dd, closeMask);
  FaceChain<Q, 0>::go(ux, uy, uz, dd, wj, anyInside);
  AddChain<Q, 0>::go(wjLDS, p, wj);
}

// cold path: recompute a face at runtime, inside-formula accumulate
__device__ void inside_face_rt(int f, const float4* vpos,
    float qx, float qy, float qz, float* wjLDS, int p)
{
  int f0 = FR[f][0], f1 = FR[f][1], f2 = FR[f][2];
  float4 v0 = vpos[f0], v1 = vpos[f1], v2 = vpos[f2];
  float a0x = v0.x - qx, a0y = v0.y - qy, a0z = v0.z - qz;
  float a1x = v1.x - qx, a1y = v1.y - qy, a1z = v1.z - qz;
  float a2x = v2.x - qx, a2y = v2.y - qy, a2z = v2.z - qz;
  float ss0 = fmaf(a0x, a0x, fmaf(a0y, a0y, a0z * a0z));
  float ss1 = fmaf(a1x, a1x, fmaf(a1y, a1y, a1z * a1z));
  float ss2 = fmaf(a2x, a2x, fmaf(a2y, a2y, a2z * a2z));
  float i0 = rsq_f(ss0), i1 = rsq_f(ss1), i2 = rsq_f(ss2);
  float d0 = ss0 * i0, d1 = ss1 * i1, d2 = ss2 * i2;
  float u0x = a0x * i0, u0y = a0y * i0, u0z = a0z * i0;
  float u1x = a1x * i1, u1y = a1y * i1, u1z = a1z * i1;
  float u2x = a2x * i2, u2y = a2y * i2, u2z = a2z * i2;
  float ex = u1x - u2x, ey = u1y - u2y, ez = u1z - u2z;
  float x0 = 0.5f * sqrt_f(fmaf(ex, ex, fmaf(ey, ey, ez * ez)));
  ex = u2x - u0x; ey = u2y - u0y; ez = u2z - u0z;
  float x1 = 0.5f * sqrt_f(fmaf(ex, ex, fmaf(ey, ey, ez * ez)));
  ex = u0x - u1x; ey = u0y - u1y; ez = u0z - u1z;
  float x2 = 0.5f * sqrt_f(fmaf(ex, ex, fmaf(ey, ey, ez * ez)));
  if (x0 >= 1.f) x0 = 0.99999f;
  if (x1 >= 1.f) x1 = 0.99999f;
  if (x2 >= 1.f) x2 = 0.99999f;
  float th0 = theta_from_x(x0), th1 = theta_from_x(x1), th2 = theta_from_x(x2);
  float hh = 0.5f * ((th0 + th1) + th2);
  if (3.14159265358979f - hh < 1e-4f) {
    float cx0 = sqrt_f(fmaxf(fmaf(-x0, x0, 1.f), 0.f));
    float cx1 = sqrt_f(fmaxf(fmaf(-x1, x1, 1.f), 0.f));
    float cx2 = sqrt_f(fmaxf(fmaf(-x2, x2, 1.f), 0.f));
    atomicAdd(&wjLDS[f0 * WST + p], (2.f * (x0 * cx0) * d2) * d1);
    atomicAdd(&wjLDS[f1 * WST + p], (2.f * (x1 * cx1) * d0) * d2);
    atomicAdd(&wjLDS[f2 * WST + p], (2.f * (x2 * cx2) * d1) * d0);
  }
}

// ---------------- Kernel D: MVC weights + deformed ----------------
__global__ __launch_bounds__(512, 4) void mvc_kernel(
    const float* __restrict__ src,      // (B,3,N)
    const float* __restrict__ cage_t,   // (B,42,3)
    const float* __restrict__ ncage_t,  // (B,42,3)
    float* __restrict__ out_def,        // (B,3,N)
    float* __restrict__ out_w)          // (B,N,42)
{
  __shared__ float4 vpos[NV];
  __shared__ float4 npos[NV];
  __shared__ float wjLDS[NV * WST];
  __shared__ int insideL[PPB];
  __shared__ unsigned int closeL[2 * PPB];
  __shared__ int blkIn;

  int tid = threadIdx.x;
  int p = tid & (PPB - 1);
  int q = tid >> 6;
  int b    = blockIdx.x / (NP / PPB);
  int pblk = blockIdx.x % (NP / PPB);
  int gp   = pblk * PPB + p;

  if (tid < NV) {
    const float* cp = cage_t + (size_t)b * NV * 3 + tid * 3;
    vpos[tid] = make_float4(cp[0], cp[1], cp[2], 0.f);
    const float* np_ = ncage_t + (size_t)b * NV * 3 + tid * 3;
    npos[tid] = make_float4(np_[0], np_[1], np_[2], 0.f);
  }
  for (int i = tid; i < NV * WST; i += 512) wjLDS[i] = 0.f;
  if (tid < PPB) insideL[tid] = 0;
  if (tid < 2 * PPB) closeL[tid] = 0u;
  if (tid == 0) blkIn = 0;
  __syncthreads();

  float qx = src[(size_t)b * 3 * NP + gp];
  float qy = src[(size_t)b * 3 * NP + NP + gp];
  float qz = src[(size_t)b * 3 * NP + 2 * NP + gp];

  int anyInside = 0;
  unsigned long long closeMask = 0ull;

  switch (q) {
    case 0: do_chunk<0>(vpos, qx, qy, qz, wjLDS, p, anyInside, closeMask); break;
    case 1: do_chunk<1>(vpos, qx, qy, qz, wjLDS, p, anyInside, closeMask); break;
    case 2: do_chunk<2>(vpos, qx, qy, qz, wjLDS, p, anyInside, closeMask); break;
    case 3: do_chunk<3>(vpos, qx, qy, qz, wjLDS, p, anyInside, closeMask); break;
    case 4: do_chunk<4>(vpos, qx, qy, qz, wjLDS, p, anyInside, closeMask); break;
    case 5: do_chunk<5>(vpos, qx, qy, qz, wjLDS, p, anyInside, closeMask); break;
    case 6: do_chunk<6>(vpos, qx, qy, qz, wjLDS, p, anyInside, closeMask); break;
    default: do_chunk<7>(vpos, qx, qy, qz, wjLDS, p, anyInside, closeMask); break;
  }

  if (anyInside) { insideL[p] = 1; blkIn = 1; }   // benign same-value races
  if (closeMask) {
    atomicOr(&closeL[p], (unsigned int)closeMask);
    atomicOr(&closeL[PPB + p], (unsigned int)(closeMask >> 32));
  }
  __syncthreads();

  if (blkIn) {   // cold: exact `where(inside, ...)` semantics
    if (tid < PPB && insideL[tid])
      for (int c = 0; c < NV; c++) wjLDS[c * WST + tid] = 0.f;
    __syncthreads();
    if (insideL[p])
      for (int f = q * CHF; f < q * CHF + CHF; f++)
        inside_face_rt(f, vpos, qx, qy, qz, wjLDS, p);
    __syncthreads();
  }
  __syncthreads();

  if (tid < PPB) {
    unsigned long long mCl =
        (unsigned long long)closeL[tid] |
        ((unsigned long long)closeL[PPB + tid] << 32);
    float sum = 0.f;
    for (int c = 0; c < NV; c++) {
      float v = wjLDS[c * WST + tid];
      if (mCl) { v = ((mCl >> c) & 1ull) ? 1.f : 0.f; wjLDS[c * WST + tid] = v; }
      sum += v;
    }
    if (sum == 0.f) sum = 1.f;
    float inv = rcp_f(sum);
    float ax = 0.f, ay = 0.f, az = 0.f;
    for (int c = 0; c < NV; c++) {
      float w = wjLDS[c * WST + tid] * inv;
      wjLDS[c * WST + tid] = w;
      float4 n = npos[c];
      ax = fmaf(w, n.x, ax);
      ay = fmaf(w, n.y, ay);
      az = fmaf(w, n.z, az);
    }
    int gpp = pblk * PPB + tid;
    out_def[(size_t)b * 3 * NP + gpp]          = ax;
    out_def[(size_t)b * 3 * NP + NP + gpp]     = ay;
    out_def[(size_t)b * 3 * NP + 2 * NP + gpp] = az;
  }
  __syncthreads();

  float* wbase = out_w + ((size_t)b * NP + pblk * PPB) * NV;
  for (int idx = tid; idx < PPB * NV; idx += 512) {
    int pp = idx / NV;
    int c  = idx - pp * NV;
    wbase[idx] = wjLDS[c * WST + pp];
  }
}

// ---------------- Kernel A: cage_opt (blocks < 672) + MLP L1-L3 (blocks >= 672)
__global__ __launch_bounds__(256) void cage_mlp_kernel(
    const float* __restrict__ tmpl, const float* __restrict__ src,
    const float* __restrict__ sf, const float* __restrict__ tf,
    const float* __restrict__ W1, const float* __restrict__ b1,
    const float* __restrict__ W2, const float* __restrict__ b2,
    const float* __restrict__ W3, const float* __restrict__ b3,
    float* __restrict__ cage,    // (B,3,42) scratch
    float* __restrict__ h3)      // (B,256) scratch
{
  __shared__ float red[8];
  __shared__ float sA[512];
  __shared__ float sB[512];
  int tid = threadIdx.x;

  if (blockIdx.x < BB * NV) {
    int b = blockIdx.x / NV;
    int v = blockIdx.x % NV;
    const float* sp = src + (size_t)b * 3 * NP;
    float cx = tmpl[v], cy = tmpl[NV + v], cz = tmpl[2 * NV + v];
    int k = 0;
    while (true) {
      float m = 3.4e38f;
      for (int i = tid; i < NP; i += 256) {
        float dx = __fsub_rn(cx, sp[i]);
        float dy = __fsub_rn(cy, sp[NP + i]);
        float dz = __fsub_rn(cz, sp[2 * NP + i]);
        float ss = __fadd_rn(__fadd_rn(__fmul_rn(dx, dx), __fmul_rn(dy, dy)),
                             __fmul_rn(dz, dz));
        m = fminf(m, ss);
      }
      #pragma unroll
      for (int off = 32; off > 0; off >>= 1)
        m = fminf(m, __shfl_down(m, off, 64));
      int wid = tid >> 6;
      __syncthreads();
      if ((tid & 63) == 0) red[wid] = m;
      __syncthreads();
      if (tid == 0) {
        float mm = fminf(fminf(red[0], red[1]), fminf(red[2], red[3]));
        red[4] = sqrtf(mm);
      }
      __syncthreads();
      float mind = red[4];
      if (mind > 0.4f && k < 100) {
        cx = __fsub_rn(cx, __fmul_rn(0.01f, cx));
        cy = __fsub_rn(cy, __fmul_rn(0.01f, cy));
        cz = __fsub_rn(cz, __fmul_rn(0.01f, cz));
        k++;
      } else {
        break;
      }
    }
    if (tid == 0) {
      cage[(size_t)b * 3 * NV + v]          = cx;
      cage[(size_t)b * 3 * NV + NV + v]     = cy;
      cage[(size_t)b * 3 * NV + 2 * NV + v] = cz;
    }
  } else {
    int bb = blockIdx.x - BB * NV;
    for (int i = tid; i < 512; i += 256)
      sA[i] = (i < FEAT) ? sf[(size_t)bb * FEAT + i]
                         : tf[(size_t)bb * FEAT + i - FEAT];
    __syncthreads();
    // L1: 512->512
    {
      int o0 = tid, o1 = tid + 256;
      float a0 = b1[o0], a1 = b1[o1];
      #pragma unroll 4
      for (int i = 0; i < 512; i++) {
        float s = sA[i];
        a0 = fmaf(s, W1[(size_t)i * 512 + o0], a0);
        a1 = fmaf(s, W1[(size_t)i * 512 + o1], a1);
      }
      sB[o0] = fmaxf(a0, 0.f);
      sB[o1] = fmaxf(a1, 0.f);
    }
    __syncthreads();
    // L2: 512->512
    {
      int o0 = tid, o1 = tid + 256;
      float a0 = b2[o0], a1 = b2[o1];
      #pragma unroll 4
      for (int i = 0; i < 512; i++) {
        float s = sB[i];
        a0 = fmaf(s, W2[(size_t)i * 512 + o0], a0);
        a1 = fmaf(s, W2[(size_t)i * 512 + o1], a1);
      }
      sA[o0] = fmaxf(a0, 0.f);
      sA[o1] = fmaxf(a1, 0.f);
    }
    __syncthreads();
    // L3: 512->256
    {
      float a0 = b3[tid];
      #pragma unroll 4
      for (int i = 0; i < 512; i++)
        a0 = fmaf(sA[i], W3[(size_t)i * 256 + tid], a0);
      h3[(size_t)bb * 256 + tid] = fmaxf(a0, 0.f);
    }
  }
}

// ---------------- L4 + cage finalize (grid B, 128 thr) ----------------
__global__ __launch_bounds__(128) void l4_finalize_kernel(
    const float* __restrict__ h3,     // (B,256)
    const float* __restrict__ W4, const float* __restrict__ b4,
    const float* __restrict__ cage,   // (B,3,42) scratch
    float* __restrict__ out_io,       // (B,126)
    float* __restrict__ cage_t,       // (B,42,3)
    float* __restrict__ ncage_t)      // (B,42,3)
{
  __shared__ float sIn[256];
  int bb = blockIdx.x;
  int tid = threadIdx.x;
  sIn[tid] = h3[(size_t)bb * 256 + tid];
  sIn[tid + 128] = h3[(size_t)bb * 256 + tid + 128];
  __syncthreads();
  if (tid < 126) {
    float acc = b4[tid];
    const float* wp = W4 + tid;
    #pragma unroll 4
    for (int i = 0; i < 256; i++) acc = fmaf(sIn[i], wp[(size_t)i * 126], acc);
    out_io[(size_t)bb * 126 + tid] = acc;
    float c  = cage[(size_t)bb * 126 + tid];
    float nc = c + acc;
    int d = tid / NV, v = tid - d * NV;
    cage_t[(size_t)bb * NV * 3 + v * 3 + d]  = c;
    ncage_t[(size_t)bb * NV * 3 + v * 3 + d] = nc;
  }
}

extern "C" void kernel_launch(void* const* d_in, const int* in_sizes, int n_in,
                              void* d_out, int out_size, void* d_ws, size_t ws_size,
                              hipStream_t stream) {
  (void)in_sizes; (void)n_in; (void)out_size; (void)d_ws; (void)ws_size;
  const float* src   = (const float*)d_in[0];
  const float* sf    = (const float*)d_in[2];
  const float* tf    = (const float*)d_in[3];
  const float* tmpl  = (const float*)d_in[4];
  const float* W1 = (const float*)d_in[6];  const float* b1 = (const float*)d_in[7];
  const float* W2 = (const float*)d_in[8];  const float* b2 = (const float*)d_in[9];
  const float* W3 = (const float*)d_in[10]; const float* b3 = (const float*)d_in[11];
  const float* W4 = (const float*)d_in[12]; const float* b4 = (const float*)d_in[13];

  float* out = (float*)d_out;
  float* out_cage_t  = out;                 // (16,42,3)   2016
  float* out_ncage_t = out + 2016;          // (16,42,3)   2016
  float* out_def     = out + 4032;          // (16,3,8192) 393216
  float* out_w       = out + 397248;        // (16,8192,42) 5505024
  float* out_io      = out + 5902272;       // (16,126)    2016

  // scratch carved out of the weights region (fully overwritten by mvc_kernel)
  float* s_cage = out_w;           // 2016
  float* s_h3   = out_w + 2016;    // 4096

  cage_mlp_kernel<<<dim3(BB * NV + BB), dim3(256), 0, stream>>>(
      tmpl, src, sf, tf, W1, b1, W2, b2, W3, b3, s_cage, s_h3);
  l4_finalize_kernel<<<dim3(BB), dim3(128), 0, stream>>>(
      s_h3, W4, b4, s_cage, out_io, out_cage_t, out_ncage_t);
  mvc_kernel<<<dim3(BB * (NP / PPB)), dim3(512), 0, stream>>>(
      src, out_cage_t, out_ncage_t, out_def, out_w);
}